// Round 1
// 577.205 us; speedup vs baseline: 1.1297x; 1.1297x over previous
//
#include <hip/hip_runtime.h>
#include <math.h>

// Problem constants
#define TSEQ   1024
#define DMODEL 256
#define NHEAD  8
#define DHEAD  32
#define NREL   2047
#define OUT0   2097152   // B*T*D elements (output 0 size)

// workspace offsets (floats); total = 9,436,672 floats = 37.75 MB
#define Q_OFF   0u
#define K_OFF   2097152u   // now holds khi/klo (bf16 as ushort), exactly fills old K region
#define V_OFF   4194304u
#define P_OFF   6291456u   // now holds phi/plo (bf16 as ushort), exactly fills old P region
#define O_OFF   6815488u
#define PE_OFF  8912640u

typedef __attribute__((ext_vector_type(8))) short bf16x8;   // 8 bf16 = 4 VGPRs
typedef __attribute__((ext_vector_type(4))) float f32x4;    // MFMA accumulator

#define MFMA16 __builtin_amdgcn_mfma_f32_16x16x32_bf16

// split fp32 x into bf16 hi + bf16 lo (x ~= hi + lo, dropped part ~2^-18*x)
__device__ __forceinline__ void split2(float x, unsigned short& h, unsigned short& l) {
  unsigned u = __float_as_uint(x);
  unsigned r = (u + 0x7fffu + ((u >> 16) & 1u)) >> 16;   // RTN to bf16
  h = (unsigned short)r;
  float res = x - __uint_as_float(r << 16);
  unsigned u2 = __float_as_uint(res);
  l = (unsigned short)((u2 + 0x7fffu + ((u2 >> 16) & 1u)) >> 16);
}

__device__ __forceinline__ void cvt8(const float* x, bf16x8& h8, bf16x8& l8) {
#pragma unroll
  for (int e = 0; e < 8; ++e) {
    unsigned short a, b;
    split2(x[e], a, b);
    h8[e] = (short)a;
    l8[e] = (short)b;
  }
}

// ---------------------------------------------------------------------------
// Sinusoidal relative PE table, fp32.
__global__ __launch_bounds__(256) void pe_kernel(float* __restrict__ pe) {
  int idx = blockIdx.x * 256 + threadIdx.x;
  int r = idx >> 8;
  int col = idx & 255;
  int m2 = col >> 1;
  float denom = exp2f((float)m2 * -0.10381025296523007f);
  float ang = (float)(r - 1023) * denom;
  pe[idx] = (col & 1) ? cosf(ang) : sinf(ang);
}

// ---------------------------------------------------------------------------
// QKV projection. Q,V written fp32 as before; K written pre-split bf16 hi/lo.
__global__ __launch_bounds__(256) void proj_qkv_kernel(
    const float* __restrict__ X,
    const float* __restrict__ Wq, const float* __restrict__ Wk, const float* __restrict__ Wv,
    const float* __restrict__ bq, const float* __restrict__ bk, const float* __restrict__ bv,
    float* __restrict__ qbuf, unsigned short* __restrict__ khi,
    unsigned short* __restrict__ klo, float* __restrict__ vbuf)
{
  __shared__ float Xs[32][68];
  __shared__ float Ws[32][68];
  const int bm = blockIdx.x;
  const int bn = blockIdx.y;
  const int sel = bn >> 2;
  const float* W   = sel == 0 ? Wq : (sel == 1 ? Wk : Wv);
  const float* bia = sel == 0 ? bq : (sel == 1 ? bk : bv);
  float* fdst      = sel == 0 ? qbuf : vbuf;
  const int c0  = (bn & 3) * 64;
  const int bt0 = bm * 64;
  const int tid = threadIdx.x;
  const int tx = tid & 15, ty = tid >> 4;
  float acc[4][4] = {};

  for (int k0 = 0; k0 < 256; k0 += 32) {
    __syncthreads();
    int c = tid;
    for (int l = 0; l < 2; ++l, c += 256) {
      int row = c >> 3, kq = (c & 7) * 4;
      float4 x4 = *(const float4*)&X[(size_t)(bt0 + row) * 256 + k0 + kq];
      Xs[kq + 0][row] = x4.x; Xs[kq + 1][row] = x4.y;
      Xs[kq + 2][row] = x4.z; Xs[kq + 3][row] = x4.w;
    }
    c = tid;
    for (int l = 0; l < 2; ++l, c += 256) {
      int row = c >> 3, kq = (c & 7) * 4;
      float4 w4 = *(const float4*)&W[(size_t)(c0 + row) * 256 + k0 + kq];
      Ws[kq + 0][row] = w4.x; Ws[kq + 1][row] = w4.y;
      Ws[kq + 2][row] = w4.z; Ws[kq + 3][row] = w4.w;
    }
    __syncthreads();
#pragma unroll
    for (int kk = 0; kk < 32; ++kk) {
      float4 a4 = *(const float4*)&Xs[kk][ty * 4];
      float4 b4 = *(const float4*)&Ws[kk][tx * 4];
      float av[4] = {a4.x, a4.y, a4.z, a4.w};
      float bv_[4] = {b4.x, b4.y, b4.z, b4.w};
#pragma unroll
      for (int i = 0; i < 4; ++i)
#pragma unroll
        for (int j = 0; j < 4; ++j) acc[i][j] += av[i] * bv_[j];
    }
  }
#pragma unroll
  for (int j = 0; j < 4; ++j) {
    int dcol = c0 + tx * 4 + j;
    float bz = bia[dcol];
    int hh = dcol >> 5, dd = dcol & 31;
#pragma unroll
    for (int i = 0; i < 4; ++i) {
      int bt = bt0 + ty * 4 + i;
      int bb = bt >> 10, t = bt & 1023;
      const size_t o = (((size_t)bb * NHEAD + hh) * TSEQ + t) * DHEAD + dd;
      const float val = acc[i][j] + bz;
      if (sel == 1) {
        unsigned short a2, b2;
        split2(val, a2, b2);
        khi[o] = a2;
        klo[o] = b2;
      } else {
        fdst[o] = val;
      }
    }
  }
}

// ---------------------------------------------------------------------------
// P projection: stores pre-split bf16 hi/lo [H][NREL][DH]
__global__ __launch_bounds__(256) void pgemm_kernel(
    const float* __restrict__ pe, const float* __restrict__ Wp,
    unsigned short* __restrict__ phi, unsigned short* __restrict__ plo)
{
  __shared__ float Xs[32][68];
  __shared__ float Ws[32][68];
  const int bm = blockIdx.x;
  const int bn = blockIdx.y;
  const int c0  = bn * 64;
  const int bt0 = bm * 64;
  const int tid = threadIdx.x;
  const int tx = tid & 15, ty = tid >> 4;
  float acc[4][4] = {};

  for (int k0 = 0; k0 < 256; k0 += 32) {
    __syncthreads();
    int c = tid;
    for (int l = 0; l < 2; ++l, c += 256) {
      int row = c >> 3, kq = (c & 7) * 4;
      int rgg = bt0 + row; if (rgg > 2046) rgg = 2046;
      float4 x4 = *(const float4*)&pe[(size_t)rgg * 256 + k0 + kq];
      Xs[kq + 0][row] = x4.x; Xs[kq + 1][row] = x4.y;
      Xs[kq + 2][row] = x4.z; Xs[kq + 3][row] = x4.w;
    }
    c = tid;
    for (int l = 0; l < 2; ++l, c += 256) {
      int row = c >> 3, kq = (c & 7) * 4;
      float4 w4 = *(const float4*)&Wp[(size_t)(c0 + row) * 256 + k0 + kq];
      Ws[kq + 0][row] = w4.x; Ws[kq + 1][row] = w4.y;
      Ws[kq + 2][row] = w4.z; Ws[kq + 3][row] = w4.w;
    }
    __syncthreads();
#pragma unroll
    for (int kk = 0; kk < 32; ++kk) {
      float4 a4 = *(const float4*)&Xs[kk][ty * 4];
      float4 b4 = *(const float4*)&Ws[kk][tx * 4];
      float av[4] = {a4.x, a4.y, a4.z, a4.w};
      float bv_[4] = {b4.x, b4.y, b4.z, b4.w};
#pragma unroll
      for (int i = 0; i < 4; ++i)
#pragma unroll
        for (int j = 0; j < 4; ++j) acc[i][j] += av[i] * bv_[j];
    }
  }
#pragma unroll
  for (int j = 0; j < 4; ++j) {
    int dcol = c0 + tx * 4 + j;
    int hh = dcol >> 5, dd = dcol & 31;
#pragma unroll
    for (int i = 0; i < 4; ++i) {
      int rr = bt0 + ty * 4 + i;
      if (rr < NREL) {
        unsigned short a2, b2;
        split2(acc[i][j], a2, b2);
        const size_t o = ((size_t)hh * NREL + rr) * DHEAD + dd;
        phi[o] = a2;
        plo[o] = b2;
      }
    }
  }
}

// ---------------------------------------------------------------------------
// MFMA attention. One block = (b,h, 64-row i-tile); 4 waves, wave w owns rows
// 16w..16w+15 as mfma_f32_16x16x32_bf16 A-fragments (split hi/lo for fp32-level
// accuracy: hi*hi + lo*hi + hi*lo). Two sweeps over 64-col j-tiles:
//  sweep 1: S = (q+u)K^T via MFMA; rel-pos M-chunk (64x128, covers the 127
//           diagonals this tile needs) via MFMA -> LDS -> diagonal gather onto
//           S fragments; online per-lane max/sum (merged across the 16-lane
//           row group at the end).
//  sweep 2: recompute S+pos (MFMA is ~free), normalize, write probs tile to
//           LDS; global attn store from LDS (dwordx4, 256B runs); AV as MFMA
//           with probs(A, split hi/lo) x V(B from fp32 LDS transpose, split),
//           accumulated in registers across all j-tiles.
__global__ __launch_bounds__(256, 2) void attn_kernel(
    const float* __restrict__ qbuf,
    const unsigned short* __restrict__ khi, const unsigned short* __restrict__ klo,
    const float* __restrict__ vbuf,
    const unsigned short* __restrict__ phi, const unsigned short* __restrict__ plo,
    const float* __restrict__ ub, const float* __restrict__ vbias,
    float* __restrict__ attn_out, float* __restrict__ obuf)
{
  __shared__ float smem[14976];          // 59.9 KB -> 2 blocks/CU
  float* const Mlds = smem;              // [64][132] M chunk
  float* const Pt   = smem + 8448;       // [64][68]  probs tile
  float* const VT   = smem + 12800;      // [32][68]  V^T tile

  const int orig = blockIdx.x;
  const int blk  = (orig & 7) * 128 + (orig >> 3);   // XCD swizzle (1024 % 8 == 0)
  const int bh   = blk >> 4;
  const int i0   = (blk & 15) << 6;
  const int h    = bh & 7;
  const int bb   = bh >> 3;
  const int tid  = threadIdx.x;
  const int w    = tid >> 6;             // wave 0..3
  const int lane = tid & 63;
  const int lc   = lane & 15;            // A row / B col within 16-subtile
  const int lg   = lane >> 4;            // k-group (8 elems each)

  const float* __restrict__ qrow = qbuf + (size_t)bh * (TSEQ * DHEAD);
  const unsigned short* __restrict__ kh = khi + (size_t)bh * (TSEQ * DHEAD);
  const unsigned short* __restrict__ kl = klo + (size_t)bh * (TSEQ * DHEAD);
  const float* __restrict__ vrow = vbuf + (size_t)bh * (TSEQ * DHEAD);
  const unsigned short* __restrict__ ph_ = phi + (size_t)h * ((size_t)NREL * DHEAD);
  const unsigned short* __restrict__ pl_ = plo + (size_t)h * ((size_t)NREL * DHEAD);
  float* __restrict__ arow = attn_out + (size_t)bh * ((size_t)TSEQ * TSEQ);

  // ---- prologue: build qu/qv A-fragments (row = lc, k = 8*lg + e) ----
  bf16x8 quh, qul, qvh, qvl;
  {
    float q8[8];
    const float* qp = &qrow[(size_t)(i0 + 16 * w + lc) * DHEAD + 8 * lg];
    *(float4*)&q8[0] = *(const float4*)&qp[0];
    *(float4*)&q8[4] = *(const float4*)&qp[4];
#pragma unroll
    for (int e = 0; e < 8; ++e) {
      const float uu = ub[h * DHEAD + 8 * lg + e];
      const float vv = vbias[h * DHEAD + 8 * lg + e];
      unsigned short a, b;
      split2(q8[e] + uu, a, b); quh[e] = (short)a; qul[e] = (short)b;
      split2(q8[e] + vv, a, b); qvh[e] = (short)a; qvl[e] = (short)b;
    }
  }

  const float KSC = 0.09016844136f;      // 1/(sqrt(256)*ln2)
  float m_l[4], sm_l[4];
#pragma unroll
  for (int r = 0; r < 4; ++r) { m_l[r] = -1e30f; sm_l[r] = 0.f; }

  const f32x4 zf = {0.f, 0.f, 0.f, 0.f};

  // ================= sweep 1: stats =================
  for (int t = 0; t < 16; ++t) {
    const int j0 = t * 64;
    const int r0 = i0 - j0 + 960;        // first P row of this tile's M chunk
    // M chunk (64 x 128): B cols are P rows r0..r0+127 (col 127 never gathered)
    f32x4 mf[8];
#pragma unroll
    for (int st = 0; st < 8; ++st) mf[st] = zf;
#pragma unroll
    for (int st = 0; st < 8; ++st) {
      int pr = r0 + 16 * st + lc;
      if (pr > 2046) pr = 2046;
      const size_t o = (size_t)pr * DHEAD + 8 * lg;
      const bf16x8 bh8 = *(const bf16x8*)&ph_[o];
      const bf16x8 bl8 = *(const bf16x8*)&pl_[o];
      mf[st] = MFMA16(qvh, bh8, mf[st], 0, 0, 0);
      mf[st] = MFMA16(qvl, bh8, mf[st], 0, 0, 0);
      mf[st] = MFMA16(qvh, bl8, mf[st], 0, 0, 0);
    }
    __syncthreads();                     // prev-tile gather finished
#pragma unroll
    for (int st = 0; st < 8; ++st)
#pragma unroll
      for (int r = 0; r < 4; ++r)
        Mlds[(16 * w + 4 * lg + r) * 132 + 16 * st + lc] = mf[st][r];

    // S tile (16 x 64 per wave)
    f32x4 sf[4];
#pragma unroll
    for (int st = 0; st < 4; ++st) sf[st] = zf;
#pragma unroll
    for (int st = 0; st < 4; ++st) {
      const size_t o = (size_t)(j0 + 16 * st + lc) * DHEAD + 8 * lg;
      const bf16x8 bh8 = *(const bf16x8*)&kh[o];
      const bf16x8 bl8 = *(const bf16x8*)&kl[o];
      sf[st] = MFMA16(quh, bh8, sf[st], 0, 0, 0);
      sf[st] = MFMA16(qul, bh8, sf[st], 0, 0, 0);
      sf[st] = MFMA16(quh, bl8, sf[st], 0, 0, 0);
    }
    __syncthreads();                     // M chunk visible
    // diagonal gather: pos[i][j] = M[i][(i-i0)-(j-j0)+63]
#pragma unroll
    for (int st = 0; st < 4; ++st) {
      const int jloc = 16 * st + lc;
#pragma unroll
      for (int r = 0; r < 4; ++r) {
        const int il = 16 * w + 4 * lg + r;
        sf[st][r] += Mlds[il * 132 + (il - jloc + 63)];
      }
    }
    // online per-lane stats (4 rows/lane, 4 cols each)
#pragma unroll
    for (int r = 0; r < 4; ++r) {
      const float t0 = fmaxf(fmaxf(sf[0][r], sf[1][r]), fmaxf(sf[2][r], sf[3][r]));
      const float mn = fmaxf(m_l[r], t0);
      const float ps = exp2f((sf[0][r] - mn) * KSC) + exp2f((sf[1][r] - mn) * KSC)
                     + exp2f((sf[2][r] - mn) * KSC) + exp2f((sf[3][r] - mn) * KSC);
      sm_l[r] = sm_l[r] * exp2f((m_l[r] - mn) * KSC) + ps;
      m_l[r] = mn;
    }
  }

  // merge stats across the 16-lane row group
  float m_f[4], rs[4];
#pragma unroll
  for (int r = 0; r < 4; ++r) {
    float mm = m_l[r], ss = sm_l[r];
#pragma unroll
    for (int d = 1; d < 16; d <<= 1) {
      const float om = __shfl_xor(mm, d);
      const float os = __shfl_xor(ss, d);
      const float M2 = fmaxf(mm, om);
      ss = ss * exp2f((mm - M2) * KSC) + os * exp2f((om - M2) * KSC);
      mm = M2;
    }
    m_f[r] = mm;
    rs[r] = 1.0f / ss;
  }

  // ================= sweep 2: probs + AV =================
  f32x4 of0 = zf, of1 = zf;
  for (int t = 0; t < 16; ++t) {
    const int j0 = t * 64;
    const int r0 = i0 - j0 + 960;
    // early V loads (latency hides under M recompute)
    const int idxv = tid * 2;
    const int vr1 = idxv >> 3, vd1 = (idxv & 7) * 4;
    const int vr2 = (idxv + 1) >> 3, vd2 = ((idxv + 1) & 7) * 4;
    const float4 va  = *(const float4*)&vrow[(size_t)(j0 + vr1) * DHEAD + vd1];
    const float4 vb4 = *(const float4*)&vrow[(size_t)(j0 + vr2) * DHEAD + vd2];

    f32x4 mf[8];
#pragma unroll
    for (int st = 0; st < 8; ++st) mf[st] = zf;
#pragma unroll
    for (int st = 0; st < 8; ++st) {
      int pr = r0 + 16 * st + lc;
      if (pr > 2046) pr = 2046;
      const size_t o = (size_t)pr * DHEAD + 8 * lg;
      const bf16x8 bh8 = *(const bf16x8*)&ph_[o];
      const bf16x8 bl8 = *(const bf16x8*)&pl_[o];
      mf[st] = MFMA16(qvh, bh8, mf[st], 0, 0, 0);
      mf[st] = MFMA16(qvl, bh8, mf[st], 0, 0, 0);
      mf[st] = MFMA16(qvh, bl8, mf[st], 0, 0, 0);
    }
    __syncthreads();                     // A: prev tile's Pt/VT reads done
#pragma unroll
    for (int st = 0; st < 8; ++st)
#pragma unroll
      for (int r = 0; r < 4; ++r)
        Mlds[(16 * w + 4 * lg + r) * 132 + 16 * st + lc] = mf[st][r];
    // stage V transposed
    VT[(vd1 + 0) * 68 + vr1] = va.x;
    VT[(vd1 + 1) * 68 + vr1] = va.y;
    VT[(vd1 + 2) * 68 + vr1] = va.z;
    VT[(vd1 + 3) * 68 + vr1] = va.w;
    VT[(vd2 + 0) * 68 + vr2] = vb4.x;
    VT[(vd2 + 1) * 68 + vr2] = vb4.y;
    VT[(vd2 + 2) * 68 + vr2] = vb4.z;
    VT[(vd2 + 3) * 68 + vr2] = vb4.w;

    f32x4 sf[4];
#pragma unroll
    for (int st = 0; st < 4; ++st) sf[st] = zf;
#pragma unroll
    for (int st = 0; st < 4; ++st) {
      const size_t o = (size_t)(j0 + 16 * st + lc) * DHEAD + 8 * lg;
      const bf16x8 bh8 = *(const bf16x8*)&kh[o];
      const bf16x8 bl8 = *(const bf16x8*)&kl[o];
      sf[st] = MFMA16(quh, bh8, sf[st], 0, 0, 0);
      sf[st] = MFMA16(qul, bh8, sf[st], 0, 0, 0);
      sf[st] = MFMA16(quh, bl8, sf[st], 0, 0, 0);
    }
    __syncthreads();                     // B: M + VT visible
#pragma unroll
    for (int st = 0; st < 4; ++st) {
      const int jloc = 16 * st + lc;
#pragma unroll
      for (int r = 0; r < 4; ++r) {
        const int il = 16 * w + 4 * lg + r;
        const float sv = sf[st][r] + Mlds[il * 132 + (il - jloc + 63)];
        const float p = exp2f((sv - m_f[r]) * KSC) * rs[r];
        Pt[il * 68 + jloc] = p;
      }
    }
    __syncthreads();                     // C: probs tile complete
    // global attn store (256B runs per row quarter)
    {
      const int prow = tid >> 2, cb = (tid & 3) * 16;
      float* gp = &arow[(size_t)(i0 + prow) * TSEQ + j0 + cb];
      const float* sp = &Pt[prow * 68 + cb];
#pragma unroll
      for (int qq = 0; qq < 4; ++qq)
        *(float4*)&gp[qq * 4] = *(const float4*)&sp[qq * 4];
    }
    // AV: O[16x32] += probs(16x64) x V(64x32)
#pragma unroll
    for (int kc = 0; kc < 2; ++kc) {
      float tmp[8];
      const float* ap = &Pt[(16 * w + lc) * 68 + 32 * kc + 8 * lg];
      *(float4*)&tmp[0] = *(const float4*)&ap[0];
      *(float4*)&tmp[4] = *(const float4*)&ap[4];
      bf16x8 ah, al;
      cvt8(tmp, ah, al);
#pragma unroll
      for (int ds = 0; ds < 2; ++ds) {
        float tv[8];
        const float* vp = &VT[(lc + 16 * ds) * 68 + 32 * kc + 8 * lg];
        *(float4*)&tv[0] = *(const float4*)&vp[0];
        *(float4*)&tv[4] = *(const float4*)&vp[4];
        bf16x8 vh, vl;
        cvt8(tv, vh, vl);
        if (ds == 0) {
          of0 = MFMA16(ah, vh, of0, 0, 0, 0);
          of0 = MFMA16(al, vh, of0, 0, 0, 0);
          of0 = MFMA16(ah, vl, of0, 0, 0, 0);
        } else {
          of1 = MFMA16(ah, vh, of1, 0, 0, 0);
          of1 = MFMA16(al, vh, of1, 0, 0, 0);
          of1 = MFMA16(ah, vl, of1, 0, 0, 0);
        }
      }
    }
  }

  // write O head slice
#pragma unroll
  for (int r = 0; r < 4; ++r) {
    const int row = i0 + 16 * w + 4 * lg + r;
    float* op = &obuf[((size_t)bb * TSEQ + row) * DMODEL + h * DHEAD];
    op[lc]      = of0[r];
    op[lc + 16] = of1[r];
  }
}

// ---------------------------------------------------------------------------
// Output projection (unchanged)
__global__ __launch_bounds__(256) void oproj_kernel(
    const float* __restrict__ A, const float* __restrict__ Wo, const float* __restrict__ bo,
    float* __restrict__ out)
{
  __shared__ float Xs[32][68];
  __shared__ float Ws[32][68];
  const int bm = blockIdx.x;
  const int bn = blockIdx.y;
  const int c0  = bn * 64;
  const int bt0 = bm * 64;
  const int tid = threadIdx.x;
  const int tx = tid & 15, ty = tid >> 4;
  float acc[4][4] = {};

  for (int k0 = 0; k0 < 256; k0 += 32) {
    __syncthreads();
    int c = tid;
    for (int l = 0; l < 2; ++l, c += 256) {
      int row = c >> 3, kq = (c & 7) * 4;
      float4 x4 = *(const float4*)&A[(size_t)(bt0 + row) * 256 + k0 + kq];
      Xs[kq + 0][row] = x4.x; Xs[kq + 1][row] = x4.y;
      Xs[kq + 2][row] = x4.z; Xs[kq + 3][row] = x4.w;
    }
    c = tid;
    for (int l = 0; l < 2; ++l, c += 256) {
      int row = c >> 3, kq = (c & 7) * 4;
      float4 w4 = *(const float4*)&Wo[(size_t)(c0 + row) * 256 + k0 + kq];
      Ws[kq + 0][row] = w4.x; Ws[kq + 1][row] = w4.y;
      Ws[kq + 2][row] = w4.z; Ws[kq + 3][row] = w4.w;
    }
    __syncthreads();
#pragma unroll
    for (int kk = 0; kk < 32; ++kk) {
      float4 a4 = *(const float4*)&Xs[kk][ty * 4];
      float4 b4 = *(const float4*)&Ws[kk][tx * 4];
      float av[4] = {a4.x, a4.y, a4.z, a4.w};
      float bv_[4] = {b4.x, b4.y, b4.z, b4.w};
#pragma unroll
      for (int i = 0; i < 4; ++i)
#pragma unroll
        for (int j = 0; j < 4; ++j) acc[i][j] += av[i] * bv_[j];
    }
  }
#pragma unroll
  for (int j = 0; j < 4; ++j) {
    int dcol = c0 + tx * 4 + j;
    float bz = bo[dcol];
#pragma unroll
    for (int i = 0; i < 4; ++i) {
      int bt = bt0 + ty * 4 + i;
      out[(size_t)bt * DMODEL + dcol] = acc[i][j] + bz;
    }
  }
}

// ---------------------------------------------------------------------------
extern "C" void kernel_launch(void* const* d_in, const int* in_sizes, int n_in,
                              void* d_out, int out_size, void* d_ws, size_t ws_size,
                              hipStream_t stream) {
  const float* X   = (const float*)d_in[0];
  const float* Wq  = (const float*)d_in[1];
  const float* bq  = (const float*)d_in[2];
  const float* Wk  = (const float*)d_in[3];
  const float* bk  = (const float*)d_in[4];
  const float* Wv  = (const float*)d_in[5];
  const float* bv  = (const float*)d_in[6];
  const float* Wp  = (const float*)d_in[7];
  const float* Wo  = (const float*)d_in[8];
  const float* bo  = (const float*)d_in[9];
  const float* ub  = (const float*)d_in[10];
  const float* vbb = (const float*)d_in[11];

  float* ws = (float*)d_ws;
  float* qbuf = ws + Q_OFF;
  unsigned short* khi = (unsigned short*)(ws + K_OFF);
  unsigned short* klo = khi + 2097152u;          // B*H*T*DH bf16 elems
  float* vbuf = ws + V_OFF;
  unsigned short* phi = (unsigned short*)(ws + P_OFF);
  unsigned short* plo = phi + 524032u;           // H*NREL*DH bf16 elems
  float* obuf = ws + O_OFF;
  float* pe   = ws + PE_OFF;

  float* out0 = (float*)d_out;
  float* attn = out0 + OUT0;

  pe_kernel<<<2047, 256, 0, stream>>>(pe);
  proj_qkv_kernel<<<dim3(128, 12), 256, 0, stream>>>(X, Wq, Wk, Wv, bq, bk, bv,
                                                     qbuf, khi, klo, vbuf);
  pgemm_kernel<<<dim3(32, 4), 256, 0, stream>>>(pe, Wp, phi, plo);
  attn_kernel<<<1024, 256, 0, stream>>>(qbuf, khi, klo, vbuf, phi, plo, ub, vbb,
                                        attn, obuf);
  oproj_kernel<<<dim3(128, 4), 256, 0, stream>>>(obuf, Wo, bo, out0);
}